// Round 11
// baseline (2937.286 us; speedup 1.0000x reference)
//
#include <hip/hip_runtime.h>

#define NN 100000
#define NE 3200000
#define D  128
#define NBUCK 782               // buckets of 128 dst nodes (dst>>7)
#define EPB 8192                // edges per count/scatter block
#define NBLK ((NE + EPB - 1) / EPB)   // 391

typedef __attribute__((ext_vector_type(8))) short bf16x8;
typedef __attribute__((ext_vector_type(4))) float f32x4;
typedef __attribute__((ext_vector_type(2))) float f32x2;

__device__ __forceinline__ float bits2f(unsigned int u) {    // raw f32 bits
    union { unsigned int i; float f; } v; v.i = u; return v.f;
}
__device__ __forceinline__ unsigned int f2bf(float f) {      // RNE bf16
    union { float f; unsigned int i; } v; v.f = f;
    unsigned int u = v.i;
    return (u + 0x7fffu + ((u >> 16) & 1u)) >> 16;
}

// --- 0. zero gcnt + detect edge_index width (int64 -> odd int32 slots all zero) ---
__global__ __launch_bounds__(1024) void zero_detect_kernel(const int* __restrict__ ei,
        int* __restrict__ flag, int* __restrict__ gcnt) {
    int t = threadIdx.x;
    if (t < NBUCK) gcnt[t] = 0;
    if (t < 64) {
        int v = ei[2 * t + 1];
        unsigned long long ball = __ballot(v != 0);
        if (t == 0) flag[0] = (ball == 0ull) ? 1 : 0;   // 1 => int64
    }
}

// --- 1. coarse count: per-block LDS hist over 782 buckets; returned atomic = block base ---
__global__ __launch_bounds__(256) void count1_kernel(const int* __restrict__ ei,
        int* __restrict__ gcnt, unsigned short* __restrict__ blockbase,
        const int* __restrict__ flag) {
    __shared__ int h[NBUCK];
    int t = threadIdx.x, b = blockIdx.x;
    int s = flag[0];
    for (int j = t; j < NBUCK; j += 256) h[j] = 0;
    __syncthreads();
    long e0 = (long)b * EPB;
#pragma unroll
    for (int it = 0; it < EPB / 256; ++it) {
        long e = e0 + it * 256 + t;
        if (e < NE) {
            int d = s ? (int)((const long*)ei)[NE + e] : ei[NE + e];
            atomicAdd(&h[d >> 7], 1);
        }
    }
    __syncthreads();
    for (int j = t; j < NBUCK; j += 256) {
        int bb = atomicAdd(&gcnt[j], h[j]);          // bucket total ~4.1K << 65536
        blockbase[(size_t)b * NBUCK + j] = (unsigned short)bb;
    }
}

// --- 2. one-block exclusive scan of bucket counts -> gbase ---
__global__ __launch_bounds__(1024) void scanb_kernel(const int* __restrict__ gcnt,
        int* __restrict__ gbase) {
    __shared__ int s[1024];
    int t = threadIdx.x;
    s[t] = (t < NBUCK) ? gcnt[t] : 0;
    __syncthreads();
    for (int off = 1; off < 1024; off <<= 1) {
        int v = (t >= off) ? s[t - off] : 0;
        __syncthreads();
        s[t] += v;
        __syncthreads();
    }
    if (t < NBUCK) gbase[t] = (t > 0) ? s[t - 1] : 0;
    if (t == 0) gbase[NBUCK] = NE;
}

// --- 3. scatter edges into bucket-contiguous split arrays: tw u32 (src<<15|w15), td u8 (dlow) ---
__global__ __launch_bounds__(256) void scatter1_kernel(const int* __restrict__ ei,
        const float* __restrict__ ew, const int* __restrict__ gbase,
        const unsigned short* __restrict__ blockbase, const int* __restrict__ flag,
        unsigned int* __restrict__ tw, unsigned char* __restrict__ td) {
    __shared__ int gb[NBUCK];
    __shared__ unsigned short bbs[NBUCK];
    __shared__ int cur[NBUCK];
    int t = threadIdx.x, b = blockIdx.x;
    int s = flag[0];
    for (int j = t; j < NBUCK; j += 256) {
        gb[j] = gbase[j];
        bbs[j] = blockbase[(size_t)b * NBUCK + j];
        cur[j] = 0;
    }
    __syncthreads();
    long e0 = (long)b * EPB;
#pragma unroll
    for (int it = 0; it < EPB / 256; ++it) {
        long e = e0 + it * 256 + t;
        if (e < NE) {
            int src, dst;
            if (s) { src = (int)((const long*)ei)[e]; dst = (int)((const long*)ei)[NE + e]; }
            else   { src = ei[e];                     dst = ei[NE + e]; }
            float w = ew[e];
            int bkt = dst >> 7;
            int r = atomicAdd(&cur[bkt], 1);
            int pos = gb[bkt] + (int)bbs[bkt] + r;
            tw[pos] = ((unsigned int)src << 15) | (f2bf(w) >> 1);
            td[pos] = (unsigned char)(dst & 127);
        }
    }
}

// --- 4. per-bucket weighted degree -> dis = rsqrt(1 + sum w) ---
__global__ __launch_bounds__(256) void degree_kernel(const unsigned int* __restrict__ tw,
        const unsigned char* __restrict__ td, const int* __restrict__ gbase,
        float* __restrict__ dis) {
    __shared__ float ws[128];
    int t = threadIdx.x, k = blockIdx.x;
    int base = gbase[k], cnt = gbase[k + 1] - base;
    if (t < 128) ws[t] = 0.f;
    __syncthreads();
    for (int i = t; i < cnt; i += 256)
        atomicAdd(&ws[td[base + i]], bits2f(tw[base + i] << 17));
    __syncthreads();
    int node = k * 128 + t;
    if (t < 128 && node < NN) dis[node] = rsqrtf(1.0f + ws[t]);
}

// --- 5. h' = bf16(dis[row] * (x @ W)); LDS-staged coalesced uint4 store epilogue ---
__global__ __launch_bounds__(256) void mgemm_kernel(const float* __restrict__ x,
        const float* __restrict__ W, const float* __restrict__ dis,
        unsigned short* __restrict__ hb) {
    __shared__ unsigned short WT[16 * 128 * 8];    // 32 KB; reused as 128x128 u16 tile
    int t = threadIdx.x;
    {
        int n = t & 127, half = t >> 7;
        for (int it = 0; it < 8; ++it) {
            int kb = half * 8 + it;                // k-chunk 0..15
            union { unsigned short s[8]; uint4 v; } pk;
#pragma unroll
            for (int j = 0; j < 8; ++j)
                pk.s[j] = (unsigned short)f2bf(W[(kb * 8 + j) * D + n]);
            *(uint4*)&WT[(kb * 128 + n) * 8] = pk.v;
        }
    }
    __syncthreads();
    int l = t & 63, w = t >> 6;
    int q = l >> 4, m = l & 15;
    long mbase = (long)blockIdx.x * 128 + w * 32;
    long r0 = mbase + m;      if (r0 > NN - 1) r0 = NN - 1;   // clamp: no OOB reads
    long r1 = mbase + 16 + m; if (r1 > NN - 1) r1 = NN - 1;
    const float* a0p = x + r0 * D + q * 8;
    const float* a1p = x + r1 * D + q * 8;
    f32x4 acc[2][8];
#pragma unroll
    for (int mt = 0; mt < 2; ++mt)
#pragma unroll
        for (int nt = 0; nt < 8; ++nt) acc[mt][nt] = (f32x4){0.f, 0.f, 0.f, 0.f};
#pragma unroll
    for (int kc = 0; kc < 4; ++kc) {
        float4 va0 = *(const float4*)(a0p + kc * 32);
        float4 va1 = *(const float4*)(a0p + kc * 32 + 4);
        float4 vb0 = *(const float4*)(a1p + kc * 32);
        float4 vb1 = *(const float4*)(a1p + kc * 32 + 4);
        union { unsigned short s[8]; bf16x8 v; } ua, ub;
        ua.s[0] = (unsigned short)f2bf(va0.x); ua.s[1] = (unsigned short)f2bf(va0.y);
        ua.s[2] = (unsigned short)f2bf(va0.z); ua.s[3] = (unsigned short)f2bf(va0.w);
        ua.s[4] = (unsigned short)f2bf(va1.x); ua.s[5] = (unsigned short)f2bf(va1.y);
        ua.s[6] = (unsigned short)f2bf(va1.z); ua.s[7] = (unsigned short)f2bf(va1.w);
        ub.s[0] = (unsigned short)f2bf(vb0.x); ub.s[1] = (unsigned short)f2bf(vb0.y);
        ub.s[2] = (unsigned short)f2bf(vb0.z); ub.s[3] = (unsigned short)f2bf(vb0.w);
        ub.s[4] = (unsigned short)f2bf(vb1.x); ub.s[5] = (unsigned short)f2bf(vb1.y);
        ub.s[6] = (unsigned short)f2bf(vb1.z); ub.s[7] = (unsigned short)f2bf(vb1.w);
        const bf16x8* bp = (const bf16x8*)WT + (kc * 4 + q) * 128 + m;
#pragma unroll
        for (int nt = 0; nt < 8; ++nt) {
            bf16x8 bfr = bp[nt * 16];
            acc[0][nt] = __builtin_amdgcn_mfma_f32_16x16x32_bf16(ua.v, bfr, acc[0][nt], 0, 0, 0);
            acc[1][nt] = __builtin_amdgcn_mfma_f32_16x16x32_bf16(ub.v, bfr, acc[1][nt], 0, 0, 0);
        }
    }
    __syncthreads();                                 // WT dead: reuse as output tile
    unsigned short* HS = WT;                         // [128][128] u16
#pragma unroll
    for (int mt = 0; mt < 2; ++mt) {
#pragma unroll
        for (int r = 0; r < 4; ++r) {
            long grow = mbase + mt * 16 + q * 4 + r; // C/D: col=lane&15, row=quad*4+reg
            float dsc = dis[(grow < NN) ? grow : (NN - 1)];
            int lrow = w * 32 + mt * 16 + q * 4 + r;
#pragma unroll
            for (int nt = 0; nt < 8; ++nt)
                HS[lrow * 128 + nt * 16 + m] = (unsigned short)f2bf(acc[mt][nt][r] * dsc);
        }
    }
    __syncthreads();
    {
        long rowb = (long)blockIdx.x * 128;
#pragma unroll
        for (int it = 0; it < 8; ++it) {
            int idx = it * 256 + t;                  // 0..2047 = 128 rows x 16 uint4
            int lrow = idx >> 4, c16 = idx & 15;
            long grow = rowb + lrow;
            if (grow < NN)
                *(uint4*)&hb[grow * D + c16 * 8] = *(const uint4*)&HS[lrow * 128 + c16 * 8];
        }
    }
}

// --- 6. fused pull: one block per 128-node bucket; 64 KB LDS f32 accumulator;
//        per edge: gather h'[src] row + 2 conflict-free ds_add_f32 per lane.
//        slot layout: accum[n*128+l] = feat 2l, accum[n*128+64+l] = feat 2l+1. ---
__global__ __launch_bounds__(1024) void pullfuse_kernel(const unsigned int* __restrict__ hb,
        const float* __restrict__ dis, const int* __restrict__ gbase,
        const unsigned int* __restrict__ tw, const unsigned char* __restrict__ td,
        const float2* __restrict__ bias2, float* __restrict__ out) {
    __shared__ float accum[128 * 128];               // 64 KB -> 2 blocks/CU, 32 waves/CU
    int tid = threadIdx.x, k = blockIdx.x;
    int base = gbase[k], cnt = gbase[k + 1] - base;
#pragma unroll
    for (int i = 0; i < 16; ++i) accum[i * 1024 + tid] = 0.f;
    __syncthreads();
    int wv = tid >> 6, l = tid & 63;
    const unsigned int* twb = tw + base;
    const unsigned char* tdb = td + base;
    for (int b8 = wv * 8; b8 < cnt; b8 += 128) {     // 16 waves x 8 edges per round
        unsigned int c[8]; int dl[8];
#pragma unroll
        for (int j = 0; j < 8; ++j) {
            int i = b8 + j; bool ok = (i < cnt);
            c[j]  = ok ? twb[i] : 0u;                // c=0 -> w=0: harmless
            dl[j] = ok ? (int)tdb[i] : 0;
        }
        unsigned int u[8];
#pragma unroll
        for (int j = 0; j < 8; ++j) u[j] = hb[(c[j] >> 15) * 64 + l];
#pragma unroll
        for (int j = 0; j < 8; ++j) {
            float m = bits2f(c[j] << 17);
            float ax = bits2f(u[j] << 16) * m;
            float ay = bits2f(u[j] & 0xffff0000u) * m;
            float* ap = &accum[dl[j] * 128];
            atomicAdd(ap + l, ax);                   // bank = l%32: 2 lanes/bank, free
            atomicAdd(ap + 64 + l, ay);
        }
    }
    __syncthreads();
    float2 bv = bias2[l];
#pragma unroll
    for (int it = 0; it < 8; ++it) {
        int p = it * 1024 + tid;                     // 0..8191; p&63 == l
        int n = p >> 6;                              // 0..127
        long gn = (long)k * 128 + n;
        if (gn < NN) {
            unsigned int a = hb[gn * 64 + l];        // self term h'[n]
            float dn = dis[gn];
            f32x2 r;
            r.x = dn * (accum[n * 128 + l]      + bits2f(a << 16))          + bv.x;
            r.y = dn * (accum[n * 128 + 64 + l] + bits2f(a & 0xffff0000u))  + bv.y;
            __builtin_nontemporal_store(r, (f32x2*)out + (gn * 64 + l));
        }
    }
}

extern "C" void kernel_launch(void* const* d_in, const int* in_sizes, int n_in,
                              void* d_out, int out_size, void* d_ws, size_t ws_size,
                              hipStream_t stream) {
    const float* x  = (const float*)d_in[0];
    const int*   ei = (const int*)d_in[1];
    const float* ew = (const float*)d_in[2];
    const float* W  = (const float*)d_in[3];
    const float* b  = (const float*)d_in[4];
    float* out = (float*)d_out;

    // workspace (~42.6 MB): tw + td + hb coexist (fusion reads both bucketed edges and h')
    unsigned int*   tw  = (unsigned int*)d_ws;                     // NE u32 (12.8 MB)
    unsigned char*  td  = (unsigned char*)(tw + NE);               // NE u8  (3.2 MB)
    unsigned short* hb  = (unsigned short*)(td + NE);              // NN*128 bf16 (25.6 MB)
    float*          dis = (float*)(hb + (size_t)NN * D);           // NN
    int*            gcnt = (int*)(dis + NN);                       // NBUCK
    int*            gbase = gcnt + NBUCK;                          // NBUCK+1
    int*            flag = gbase + NBUCK + 1;                      // 1
    unsigned short* blockbase = (unsigned short*)(flag + 1);       // NBLK*NBUCK u16 (611 KB)

    zero_detect_kernel<<<1, 1024, 0, stream>>>(ei, flag, gcnt);
    count1_kernel<<<NBLK, 256, 0, stream>>>(ei, gcnt, blockbase, flag);
    scanb_kernel<<<1, 1024, 0, stream>>>(gcnt, gbase);
    scatter1_kernel<<<NBLK, 256, 0, stream>>>(ei, ew, gbase, blockbase, flag, tw, td);
    degree_kernel<<<NBUCK, 256, 0, stream>>>(tw, td, gbase, dis);
    mgemm_kernel<<<(NN + 127) / 128, 256, 0, stream>>>(x, W, dis, hb);
    pullfuse_kernel<<<NBUCK, 1024, 0, stream>>>((const unsigned int*)hb, dis, gbase, tw, td,
                                                (const float2*)b, out);
}